// Round 4
// baseline (6898.192 us; speedup 1.0000x reference)
//
#include <hip/hip_runtime.h>
#include <hip/hip_bf16.h>
#include <cmath>

// Problem constants
#define Bz 4
#define Tt 8192
#define Ee 512
#define Hh 8
#define Cc 256
#define KD 64          // E/H
#define HD 128         // E*VF/H
#define NC 32          // T/C
#define EV 1024        // E*VF
#define Mrows (Bz*Tt)  // 32768

typedef __hip_bfloat16 bf16;

__device__ __forceinline__ float ldf(const float* p) { return *p; }
__device__ __forceinline__ float ldf(const bf16* p) { return __bfloat162float(*p); }
__device__ __forceinline__ void stf(float* p, float v) { *p = v; }
__device__ __forceinline__ void stf(bf16* p, float v) { *p = __float2bfloat16(v); }

// ---------------------------------------------------------------------------
// Tiled GEMM: C[M,N] = A[M,K] @ W[K,N]; A is fp32 or bf16, W fp32,
// C is fp32 or bf16. 64x64 tile, BK=16, 256 threads, 4x4 micro-tile.
// ---------------------------------------------------------------------------
template <typename TA, typename TO>
__global__ __launch_bounds__(256) void gemm_t(const TA* __restrict__ A,
                                              const float* __restrict__ W,
                                              TO* __restrict__ Cmat,
                                              int M, int K, int N) {
    __shared__ __align__(16) float As[16][64];
    __shared__ __align__(16) float Bs[16][64];
    int tid = threadIdx.x;
    int n0 = blockIdx.x * 64, m0 = blockIdx.y * 64;
    int tx = tid & 15, ty = tid >> 4;
    float acc[4][4] = {};
    int am = tid >> 2, akq = (tid & 3) * 4;
    int bk = tid >> 4, bnq = (tid & 15) * 4;
    for (int k0 = 0; k0 < K; k0 += 16) {
        __syncthreads();
        const TA* ap = A + (size_t)(m0 + am) * K + k0 + akq;
        #pragma unroll
        for (int j = 0; j < 4; ++j) As[akq + j][am] = ldf(ap + j);
        *reinterpret_cast<float4*>(&Bs[bk][bnq]) =
            *reinterpret_cast<const float4*>(&W[(size_t)(k0 + bk) * N + n0 + bnq]);
        __syncthreads();
        #pragma unroll
        for (int kk = 0; kk < 16; ++kk) {
            float4 av = *reinterpret_cast<const float4*>(&As[kk][ty * 4]);
            float4 bv = *reinterpret_cast<const float4*>(&Bs[kk][tx * 4]);
            float a4[4] = {av.x, av.y, av.z, av.w};
            float b4[4] = {bv.x, bv.y, bv.z, bv.w};
            #pragma unroll
            for (int i = 0; i < 4; ++i)
                #pragma unroll
                for (int j = 0; j < 4; ++j) acc[i][j] += a4[i] * b4[j];
        }
    }
    #pragma unroll
    for (int i = 0; i < 4; ++i)
        #pragma unroll
        for (int j = 0; j < 4; ++j)
            stf(&Cmat[(size_t)(m0 + ty * 4 + i) * N + n0 + tx * 4 + j], acc[i][j]);
}

// ---------------------------------------------------------------------------
// Rotary (theta-shift) + permute (B,T,H*KD) -> (B,H,T,KD), with scale.
// ---------------------------------------------------------------------------
__global__ __launch_bounds__(256) void rotate_permute(const bf16* __restrict__ raw,
                                                      const float* __restrict__ sn,
                                                      const float* __restrict__ cs,
                                                      bf16* __restrict__ outp,
                                                      float scale) {
    size_t p = (size_t)blockIdx.x * 256 + threadIdx.x;  // pair index
    size_t e0 = p * 2;
    int kd = (int)(e0 % KD);
    int ch = (int)(e0 % Ee);
    int h = ch / KD;
    size_t bt = e0 / Ee;
    int t = (int)(bt % Tt);
    size_t b = bt / Tt;
    float x1 = ldf(raw + e0) * scale, x2 = ldf(raw + e0 + 1) * scale;
    float c1 = cs[(size_t)t * KD + kd], s1 = sn[(size_t)t * KD + kd];
    float c2 = cs[(size_t)t * KD + kd + 1], s2 = sn[(size_t)t * KD + kd + 1];
    size_t o = ((b * Hh + h) * (size_t)Tt + t) * KD + kd;
    stf(outp + o, x1 * c1 - x2 * s1);
    stf(outp + o + 1, x2 * c2 + x1 * s2);
}

// ---------------------------------------------------------------------------
// Inner attention per (b, n, h, ctile of 32 rows):
//   S[r][d] = (q_r . k_d) * mask[h][c][d];  iscale[c] = max(1, sum_d |S|)
//   ATT[b,t,h*HD+e] = (1/iscale) * sum_d S[r][d] * V[d][e]
// ---------------------------------------------------------------------------
#define CT 32
__global__ __launch_bounds__(256) void attn_inner(const bf16* __restrict__ qr,
                                                  const bf16* __restrict__ kr,
                                                  const bf16* __restrict__ vraw,
                                                  const float* __restrict__ mask,
                                                  bf16* __restrict__ ATT,
                                                  float* __restrict__ iscale_g) {
    __shared__ float sQ[CT][KD + 1];
    __shared__ float sS[CT][Cc + 1];
    __shared__ float sSlab[64 * 64];  // kr slabs (64x64) / v slabs (32x128)
    __shared__ float sRed[CT][9];
    __shared__ float sInv[CT];

    int bid = blockIdx.x;
    int ctile = bid & 7; bid >>= 3;   // C/CT = 8
    int h = bid % Hh; bid /= Hh;
    int n = bid % NC;
    int b = bid / NC;
    int tid = threadIdx.x;

    size_t qoff = (((size_t)(b * Hh + h)) * Tt + (size_t)n * Cc + ctile * CT) * KD;
    for (int i = tid; i < CT * KD; i += 256) sQ[i >> 6][i & 63] = ldf(qr + qoff + i);

    size_t koff = (((size_t)(b * Hh + h)) * Tt + (size_t)n * Cc) * KD;
    int r = tid >> 3, dl = tid & 7;
    float rowpart = 0.f;
    const float* mrow = mask + ((size_t)h * Cc + ctile * CT + r) * Cc;
    for (int ds = 0; ds < 4; ++ds) {
        __syncthreads();
        for (int i = tid; i < 64 * KD; i += 256) sSlab[i] = ldf(kr + koff + (size_t)ds * 64 * KD + i);
        __syncthreads();
        #pragma unroll
        for (int j = 0; j < 8; ++j) {
            int dIn = dl + 8 * j;
            float s = 0.f;
            #pragma unroll
            for (int k = 0; k < KD; ++k) {
                int kk = (k + dl * 8) & 63;  // bank-stagger
                s += sQ[r][kk] * sSlab[dIn * 64 + kk];
            }
            int d = ds * 64 + dIn;
            s *= mrow[d];
            sS[r][d] = s;
            rowpart += fabsf(s);
        }
    }
    sRed[r][dl] = rowpart;
    __syncthreads();
    if (tid < CT) {
        float tot = 0.f;
        #pragma unroll
        for (int j2 = 0; j2 < 8; ++j2) tot += sRed[tid][j2];
        tot = fmaxf(tot, 1.0f);
        iscale_g[(((size_t)(b * NC + n)) * Hh + h) * Cc + ctile * CT + tid] = tot;
        sInv[tid] = 1.0f / tot;
    }
    // phase 2: O = S @ V
    int e = tid & 127, rp = tid >> 7;
    float acc[16];
    #pragma unroll
    for (int i = 0; i < 16; ++i) acc[i] = 0.f;
    for (int vs = 0; vs < 8; ++vs) {
        __syncthreads();
        for (int i = tid; i < 32 * HD; i += 256) {
            int c = i >> 7, e2 = i & 127;
            sSlab[i] = ldf(vraw + ((size_t)b * Tt + (size_t)n * Cc + vs * 32 + c) * EV + h * HD + e2);
        }
        __syncthreads();
        #pragma unroll
        for (int j = 0; j < 32; ++j) {
            float vv = sSlab[j * HD + e];
            int d = vs * 32 + j;
            #pragma unroll
            for (int i = 0; i < 16; ++i) acc[i] += sS[rp + 2 * i][d] * vv;
        }
    }
    size_t obase = ((size_t)b * Tt + (size_t)n * Cc + ctile * CT);
    #pragma unroll
    for (int i = 0; i < 16; ++i) {
        int rr = rp + 2 * i;
        stf(ATT + (obase + rr) * EV + h * HD + e, acc[i] * sInv[rr]);
    }
}

// ---------------------------------------------------------------------------
// Per-chunk kv summary: kv[k][e] = sum_c kr[c][k] * v[c][e] * vid[h][c]
// ---------------------------------------------------------------------------
__global__ __launch_bounds__(256) void chunk_kv(const bf16* __restrict__ kr,
                                                const bf16* __restrict__ vraw,
                                                const float* __restrict__ vid,
                                                float* __restrict__ kv) {
    __shared__ float sK[64 * 64];
    __shared__ float sV[64 * HD];
    int bid = blockIdx.x;
    int h = bid % Hh; bid /= Hh;
    int n = bid % NC;
    int b = bid / NC;
    int tid = threadIdx.x;
    int e = tid & 127, kp = tid >> 7;
    float acc[32];
    #pragma unroll
    for (int i = 0; i < 32; ++i) acc[i] = 0.f;
    size_t koff = (((size_t)(b * Hh + h)) * Tt + (size_t)n * Cc) * KD;
    for (int cs4 = 0; cs4 < 4; ++cs4) {
        __syncthreads();
        for (int i = tid; i < 64 * KD; i += 256) sK[i] = ldf(kr + koff + (size_t)cs4 * 64 * KD + i);
        for (int i = tid; i < 64 * HD; i += 256) {
            int c = i >> 7, e2 = i & 127;
            int cg = cs4 * 64 + c;
            sV[i] = ldf(vraw + ((size_t)b * Tt + (size_t)n * Cc + cg) * EV + h * HD + e2) * vid[h * Cc + cg];
        }
        __syncthreads();
        #pragma unroll
        for (int j = 0; j < 64; ++j) {
            float vv = sV[j * HD + e];
            #pragma unroll
            for (int i = 0; i < 32; ++i) acc[i] += sK[j * KD + (kp + 2 * i)] * vv;
        }
    }
    size_t obase = (((size_t)(b * NC + n)) * Hh + h) * (size_t)(KD * HD);
    #pragma unroll
    for (int i = 0; i < 32; ++i) kv[obase + (size_t)(kp + 2 * i) * HD + e] = acc[i];
}

// ---------------------------------------------------------------------------
// Sequential scan over chunks, IN PLACE on kvbuf: per chunk n, each thread
// loads kv value, overwrites the slot with kv_rec = state/scale (pre-update),
// then updates its state.  Safe: one thread owns each slot.
// ---------------------------------------------------------------------------
__global__ __launch_bounds__(256) void scan_kv(float* __restrict__ kvbuf,
                                               const float* __restrict__ cdv,
                                               float* __restrict__ cscale) {
    int bh = blockIdx.x;
    int h = bh % Hh, b = bh / Hh;
    int tid = threadIdx.x;
    int e = tid & 127, kp = tid >> 7;
    float st[32];
    #pragma unroll
    for (int i = 0; i < 32; ++i) st[i] = 0.f;
    float scale = 1.f;
    float cd = cdv[h];
    __shared__ float part[2][128];
    __shared__ float sSc;
    for (int n = 0; n < NC; ++n) {
        size_t base = (((size_t)(b * NC + n)) * Hh + h) * (size_t)(KD * HD);
        float inv = 1.f / scale;
        float psum = 0.f;
        #pragma unroll
        for (int i = 0; i < 32; ++i) {
            size_t idx = base + (size_t)(kp + 2 * i) * HD + e;
            float kvv = kvbuf[idx];
            kvbuf[idx] = st[i] * inv;       // emit kv_recurrent (pre-update)
            float xx = st[i] * cd + kvv;
            st[i] = xx;
            psum += fabsf(xx);
        }
        if (tid == 0) cscale[(b * NC + n) * Hh + h] = scale;  // pre-update scale
        part[kp][e] = psum;
        __syncthreads();
        if (tid == 0) {
            float m = 0.f;
            for (int j = 0; j < 128; ++j) m = fmaxf(m, part[0][j] + part[1][j]);
            sSc = fmaxf(m, 1.f);
        }
        __syncthreads();
        scale = sSc;
    }
}

// ---------------------------------------------------------------------------
// Cross output + combine (RMW on bf16 ATT):
//   CO[c][e] = qid[h][c] * sum_k qr[c][k] * kv_rec[k][e]
//   ATT = ATT*(iscale/all) + CO*(cscale/all),  all = max(iscale, cscale)
// ---------------------------------------------------------------------------
__global__ __launch_bounds__(256) void cross_combine(const bf16* __restrict__ qr,
                                                     const float* __restrict__ kv_rec,
                                                     const float* __restrict__ iscale_g,
                                                     const float* __restrict__ cscale_g,
                                                     const float* __restrict__ qid,
                                                     bf16* __restrict__ ATT) {
    __shared__ float sQ2[64 * KD];
    __shared__ float sKV[KD * HD];
    int bid = blockIdx.x;
    int ctile = bid & 3; bid >>= 2;
    int h = bid % Hh; bid /= Hh;
    int n = bid % NC;
    int b = bid / NC;
    int tid = threadIdx.x;
    size_t qoff = (((size_t)(b * Hh + h)) * Tt + (size_t)n * Cc + ctile * 64) * KD;
    for (int i = tid; i < 64 * KD; i += 256) sQ2[i] = ldf(qr + qoff + i);
    size_t kvoff = (((size_t)(b * NC + n)) * Hh + h) * (size_t)(KD * HD);
    for (int i = tid; i < KD * HD; i += 256) sKV[i] = kv_rec[kvoff + i];
    __syncthreads();
    int e = tid & 127, rp = tid >> 7;
    float cscale = cscale_g[(b * NC + n) * Hh + h];
    for (int i = 0; i < 32; ++i) {
        int r = rp + 2 * i;
        float a = 0.f;
        #pragma unroll
        for (int k = 0; k < KD; ++k) a += sQ2[r * KD + k] * sKV[k * HD + e];
        int c = ctile * 64 + r;
        float isc = iscale_g[(((size_t)(b * NC + n)) * Hh + h) * Cc + c];
        float alls = fmaxf(isc, cscale);
        size_t oidx = ((size_t)b * Tt + (size_t)n * Cc + c) * EV + h * HD + e;
        float prev = ldf(ATT + oidx);
        stf(ATT + oidx, prev * (isc / alls) + qid[h * Cc + c] * a * (cscale / alls));
    }
}

// ---------------------------------------------------------------------------
// PER-HEAD RMS norm (over HD=128 channels) + SiLU(g) gate; in place over g.
// Reference: output (B,NC,C,H,HD); mean(output^2, -1) over HD, THEN reshape.
// One block per (b,t) row; thread tid covers channels [tid*4, tid*4+4) which
// all lie in head tid/32.  Reduce across the 32 threads of each head.
// ---------------------------------------------------------------------------
__global__ __launch_bounds__(256) void rms_silu(const bf16* __restrict__ ATT,
                                                bf16* __restrict__ g) {
    int row = blockIdx.x;
    int tid = threadIdx.x;
    size_t base = (size_t)row * EV + tid * 4;
    float x[4];
    float ss = 0.f;
    #pragma unroll
    for (int j = 0; j < 4; ++j) {
        x[j] = ldf(ATT + base + j);
        ss += x[j] * x[j];
    }
    // reduce within each 32-thread head group (threads of a head are
    // consecutive, so they sit in the same wave half)
    #pragma unroll
    for (int o = 16; o > 0; o >>= 1) ss += __shfl_down(ss, o, 32);
    ss = __shfl(ss, 0, 32);  // broadcast head sum to all 32 lanes of the group
    float rms = rsqrtf(ss / (float)HD + 1e-6f);
    #pragma unroll
    for (int j = 0; j < 4; ++j) {
        float gg = ldf(g + base + j);
        float sg = gg / (1.f + __expf(-gg));
        stf(g + base + j, sg * x[j] * rms);
    }
}

// ---------------------------------------------------------------------------
extern "C" void kernel_launch(void* const* d_in, const int* in_sizes, int n_in,
                              void* d_out, int out_size, void* d_ws, size_t ws_size,
                              hipStream_t stream) {
    const float* x    = (const float*)d_in[0];
    const float* sn   = (const float*)d_in[1];
    const float* cs   = (const float*)d_in[2];
    const float* mask = (const float*)d_in[3];
    const float* cdv  = (const float*)d_in[4];
    const float* qid  = (const float*)d_in[5];
    const float* vid  = (const float*)d_in[6];
    const float* Wq   = (const float*)d_in[7];
    const float* Wk   = (const float*)d_in[8];
    const float* Wv   = (const float*)d_in[9];
    const float* Wg   = (const float*)d_in[10];
    const float* Wo   = (const float*)d_in[11];
    float* out = (float*)d_out;

    // workspace layout: ~161 MB total
    char* w = (char*)d_ws;
    bf16* qr     = (bf16*)w;  w += (size_t)Bz * Hh * Tt * KD * 2;       // 33.5 MB
    bf16* kr     = (bf16*)w;  w += (size_t)Bz * Hh * Tt * KD * 2;       // 33.5 MB
    bf16* vraw   = (bf16*)w;  w += (size_t)Bz * Tt * EV * 2;            // 67 MB
    float* kvbuf = (float*)w; w += (size_t)Bz * NC * Hh * KD * HD * 4;  // 33.5 MB (kv, then kv_rec in place)
    float* iscale= (float*)w; w += (size_t)Bz * NC * Hh * Cc * 4;       // 1 MB
    float* cscale= (float*)w; w += (size_t)Bz * NC * Hh * 4;            // 4 KB

    // g projection reuses the (dead after cross_combine) qr+kr region: 67 MB.
    bf16* gbuf = qr;

    // d_out (67 MB) doubles as scratch: pre-rotate q/k GEMM output (33.5 MB bf16),
    // then the bf16 ATT buffer (exactly 67 MB); dead before the final GEMM
    // rewrites d_out in full as fp32.
    bf16* ATT   = (bf16*)d_out;
    bf16* rawQK = (bf16*)d_out;

    dim3 blk(256);
    // q/k/v projections + rotary (pre-rotate staged in d_out scratch)
    gemm_t<float, bf16><<<dim3(Ee / 64, Mrows / 64), blk, 0, stream>>>(x, Wq, rawQK, Mrows, Ee, Ee);
    rotate_permute<<<dim3((Bz * Tt * Ee) / 512), blk, 0, stream>>>(rawQK, sn, cs, qr, 1.0f);
    gemm_t<float, bf16><<<dim3(Ee / 64, Mrows / 64), blk, 0, stream>>>(x, Wk, rawQK, Mrows, Ee, Ee);
    rotate_permute<<<dim3((Bz * Tt * Ee) / 512), blk, 0, stream>>>(rawQK, sn, cs, kr, 0.125f);
    gemm_t<float, bf16><<<dim3(EV / 64, Mrows / 64), blk, 0, stream>>>(x, Wv, vraw, Mrows, Ee, EV);
    // retention
    attn_inner<<<dim3(Bz * NC * Hh * 8), blk, 0, stream>>>(qr, kr, vraw, mask, ATT, iscale);
    chunk_kv<<<dim3(Bz * NC * Hh), blk, 0, stream>>>(kr, vraw, vid, kvbuf);
    scan_kv<<<dim3(Bz * Hh), blk, 0, stream>>>(kvbuf, cdv, cscale);
    cross_combine<<<dim3(Bz * NC * Hh * 4), blk, 0, stream>>>(qr, kvbuf, iscale, cscale, qid, ATT);
    // g projection (into dead qr+kr region), epilogue
    gemm_t<float, bf16><<<dim3(EV / 64, Mrows / 64), blk, 0, stream>>>(x, Wg, gbuf, Mrows, Ee, EV);
    rms_silu<<<dim3(Bz * Tt), blk, 0, stream>>>(ATT, gbuf);
    gemm_t<bf16, float><<<dim3(Ee / 64, Mrows / 64), blk, 0, stream>>>(gbuf, Wo, out, Mrows, EV, Ee);
}

// Round 5
// 1175.282 us; speedup vs baseline: 5.8694x; 5.8694x over previous
//
#include <hip/hip_runtime.h>
#include <cmath>

// Problem constants
#define Bz 4
#define Tt 8192
#define Ee 512
#define Hh 8
#define Cc 256
#define KD 64          // E/H
#define HD 128         // E*VF/H
#define NC 32          // T/C
#define EV 1024        // E*VF
#define Mrows (Bz*Tt)  // 32768

typedef unsigned short u16;
typedef __attribute__((ext_vector_type(4))) float f32x4;
typedef __attribute__((ext_vector_type(8))) short s16x8;

__device__ __forceinline__ u16 f2b(float f) {
    union { float f; unsigned u; } v; v.f = f;
    unsigned r = v.u + 0x7FFFu + ((v.u >> 16) & 1u);
    return (u16)(r >> 16);
}
__device__ __forceinline__ float b2f(u16 u) {
    union { unsigned u; float f; } v; v.u = ((unsigned)u) << 16;
    return v.f;
}
#define MFMA16(a, b, c) __builtin_amdgcn_mfma_f32_16x16x32_bf16((a), (b), (c), 0, 0, 0)

// ---------------------------------------------------------------------------
// cast x (fp32) -> bf16, 4 elems/thread
// ---------------------------------------------------------------------------
__global__ __launch_bounds__(256) void cast_x_k(const float* __restrict__ x,
                                                u16* __restrict__ xb) {
    size_t i = ((size_t)blockIdx.x * 256 + threadIdx.x) * 4;
    float4 v = *(const float4*)(x + i);
    ushort4 o;
    o.x = f2b(v.x); o.y = f2b(v.y); o.z = f2b(v.z); o.w = f2b(v.w);
    *(ushort4*)(xb + i) = o;
}

// ---------------------------------------------------------------------------
// cast + transpose weights: W[K][N] fp32 -> Wt[N][K] bf16 (with scale)
// ---------------------------------------------------------------------------
__global__ __launch_bounds__(256) void castT_k(const float* __restrict__ W,
                                               u16* __restrict__ Wt,
                                               int K, int N, float scale) {
    __shared__ float tile[32][33];
    int k0 = blockIdx.y * 32, n0 = blockIdx.x * 32;
    int r = threadIdx.x >> 3, c4 = (threadIdx.x & 7) * 4;
    float4 v = *(const float4*)(W + (size_t)(k0 + r) * N + n0 + c4);
    tile[r][c4] = v.x; tile[r][c4 + 1] = v.y; tile[r][c4 + 2] = v.z; tile[r][c4 + 3] = v.w;
    __syncthreads();
    ushort4 o;
    o.x = f2b(tile[c4 + 0][r] * scale);
    o.y = f2b(tile[c4 + 1][r] * scale);
    o.z = f2b(tile[c4 + 2][r] * scale);
    o.w = f2b(tile[c4 + 3][r] * scale);
    *(ushort4*)(Wt + (size_t)(n0 + r) * K + k0 + c4) = o;
}

// ---------------------------------------------------------------------------
// MFMA GEMM: C[M,N] = A[M,K](bf16) @ Wt[N,K]^T(bf16).  128x128 tile, 4 waves,
// direct global->VGPR fragments (L1/L2 provide reuse).  Epilogues:
//   EPI=0: rotary + permute to (B,H,T,KD) bf16 (q/k; k-scale folded into Wt)
//   EPI=1: bf16 to natural layout is skipped; writes Vt[b,h,n][e][c] packed
//   EPI=2: plain bf16 row-major
//   EPI=3: plain fp32 row-major
// ---------------------------------------------------------------------------
template <int EPI>
__global__ __launch_bounds__(256) void gemm_mfma(const u16* __restrict__ A,
                                                 const u16* __restrict__ Bt,
                                                 void* __restrict__ Cout,
                                                 int K, int N,
                                                 const float* __restrict__ sn,
                                                 const float* __restrict__ cs) {
    int tid = threadIdx.x;
    int lane = tid & 63, wid = tid >> 6;
    int cL = lane & 15, quad = lane >> 4;
    int m0 = blockIdx.y * 128 + (wid & 1) * 64;
    int n0 = blockIdx.x * 128 + (wid >> 1) * 64;
    f32x4 acc[4][4] = {};
    for (int k0 = 0; k0 < K; k0 += 32) {
        s16x8 af[4], bfr[4];
        #pragma unroll
        for (int mt = 0; mt < 4; ++mt)
            af[mt] = *(const s16x8*)(A + (size_t)(m0 + mt * 16 + cL) * K + k0 + quad * 8);
        #pragma unroll
        for (int nt = 0; nt < 4; ++nt)
            bfr[nt] = *(const s16x8*)(Bt + (size_t)(n0 + nt * 16 + cL) * K + k0 + quad * 8);
        #pragma unroll
        for (int mt = 0; mt < 4; ++mt)
            #pragma unroll
            for (int nt = 0; nt < 4; ++nt)
                acc[mt][nt] = MFMA16(af[mt], bfr[nt], acc[mt][nt]);
    }
    if (EPI == 0) {
        u16* dst = (u16*)Cout;
        #pragma unroll
        for (int mt = 0; mt < 4; ++mt)
            #pragma unroll
            for (int nt = 0; nt < 4; ++nt)
                #pragma unroll
                for (int i = 0; i < 4; ++i) {
                    int m = m0 + mt * 16 + quad * 4 + i;
                    int n = n0 + nt * 16 + cL;
                    float v = acc[mt][nt][i];
                    float p = __shfl_xor(v, 1, 64);
                    int t = m & 8191, b = m >> 13, h = n >> 6, kd = n & 63;
                    float c1 = cs[t * 64 + kd], s1 = sn[t * 64 + kd];
                    float o = (n & 1) ? (v * c1 + p * s1) : (v * c1 - p * s1);
                    dst[(((size_t)(b * 8 + h)) * 8192 + t) * 64 + kd] = f2b(o);
                }
    } else if (EPI == 1) {
        u16* vt = (u16*)Cout;
        #pragma unroll
        for (int mt = 0; mt < 4; ++mt)
            #pragma unroll
            for (int nt = 0; nt < 4; ++nt) {
                int m = m0 + mt * 16 + quad * 4;  // i=0 row; i=0..3 consecutive t
                int n = n0 + nt * 16 + cL;
                int b = m >> 13, t = m & 8191;
                int nn = t >> 8, ccc = t & 255;
                int h = n >> 7, e = n & 127;
                ushort4 pk;
                pk.x = f2b(acc[mt][nt][0]);
                pk.y = f2b(acc[mt][nt][1]);
                pk.z = f2b(acc[mt][nt][2]);
                pk.w = f2b(acc[mt][nt][3]);
                *(ushort4*)(vt + (((size_t)((b * 8 + h) * 32 + nn)) << 15) + e * 256 + ccc) = pk;
            }
    } else if (EPI == 2) {
        u16* dst = (u16*)Cout;
        #pragma unroll
        for (int mt = 0; mt < 4; ++mt)
            #pragma unroll
            for (int nt = 0; nt < 4; ++nt)
                #pragma unroll
                for (int i = 0; i < 4; ++i)
                    dst[(size_t)(m0 + mt * 16 + quad * 4 + i) * N + n0 + nt * 16 + cL] =
                        f2b(acc[mt][nt][i]);
    } else {
        float* dst = (float*)Cout;
        #pragma unroll
        for (int mt = 0; mt < 4; ++mt)
            #pragma unroll
            for (int nt = 0; nt < 4; ++nt)
                #pragma unroll
                for (int i = 0; i < 4; ++i)
                    dst[(size_t)(m0 + mt * 16 + quad * 4 + i) * N + n0 + nt * 16 + cL] =
                        acc[mt][nt][i];
    }
}

// ---------------------------------------------------------------------------
// Inner retention, MFMA.  Block = (b, n, h, rtile of 64 rows), 4 waves.
// Phase 1: S[64][256] = Q.K^T * mask (waves own 64-col strips; strips fully
// above the diagonal are skipped).  Row |S| sums -> iscale.  S -> LDS bf16.
// Phase 2: O[64][128] = S.V (V fragments direct from global Vt[e][c]),
// K-loop truncated to the causal nonzero range.  O *= 1/iscale -> ATT.
// ---------------------------------------------------------------------------
__global__ __launch_bounds__(256) void attn_mfma(const u16* __restrict__ qr,
                                                 const u16* __restrict__ kr,
                                                 const u16* __restrict__ vt,
                                                 const float* __restrict__ mask,
                                                 u16* __restrict__ ATT,
                                                 float* __restrict__ iscale_g) {
    __shared__ u16 Ss[64][264];
    __shared__ float partial[4][64];
    __shared__ float sInvL[64];
    int bid = blockIdx.x;
    int rtile = bid & 3; bid >>= 2;
    int h = bid & 7; bid >>= 3;
    int n = bid & 31; int b = bid >> 5;
    int tid = threadIdx.x, lane = tid & 63, w = tid >> 6;
    int cL = lane & 15, quad = lane >> 4;

    size_t qkbase = ((size_t)((b * 8 + h) * 8192 + n * 256)) * 64;
    f32x4 acc[4][4] = {};
    if (w <= rtile) {
        const u16* Qb = qr + qkbase + (size_t)rtile * 64 * 64;
        const u16* Kb = kr + qkbase + (size_t)w * 64 * 64;
        #pragma unroll
        for (int kt = 0; kt < 2; ++kt) {
            s16x8 af[4], bfr[4];
            #pragma unroll
            for (int mt = 0; mt < 4; ++mt)
                af[mt] = *(const s16x8*)(Qb + (mt * 16 + cL) * 64 + kt * 32 + quad * 8);
            #pragma unroll
            for (int nt = 0; nt < 4; ++nt)
                bfr[nt] = *(const s16x8*)(Kb + (nt * 16 + cL) * 64 + kt * 32 + quad * 8);
            #pragma unroll
            for (int mt = 0; mt < 4; ++mt)
                #pragma unroll
                for (int nt = 0; nt < 4; ++nt)
                    acc[mt][nt] = MFMA16(af[mt], bfr[nt], acc[mt][nt]);
        }
    }
    float rs[4][4] = {};
    if (w <= rtile) {
        const float* mb = mask + ((size_t)h << 16);
        #pragma unroll
        for (int mt = 0; mt < 4; ++mt)
            #pragma unroll
            for (int nt = 0; nt < 4; ++nt)
                #pragma unroll
                for (int i = 0; i < 4; ++i) {
                    int r = rtile * 64 + mt * 16 + quad * 4 + i;
                    int d = w * 64 + nt * 16 + cL;
                    float s = acc[mt][nt][i] * mb[r * 256 + d];
                    Ss[mt * 16 + quad * 4 + i][w * 64 + nt * 16 + cL] = f2b(s);
                    rs[mt][i] += fabsf(s);
                }
    }
    #pragma unroll
    for (int mt = 0; mt < 4; ++mt)
        #pragma unroll
        for (int i = 0; i < 4; ++i) {
            float v = rs[mt][i];
            v += __shfl_xor(v, 1, 16);
            v += __shfl_xor(v, 2, 16);
            v += __shfl_xor(v, 4, 16);
            v += __shfl_xor(v, 8, 16);
            if (cL == 0) partial[w][mt * 16 + quad * 4 + i] = v;
        }
    __syncthreads();
    if (tid < 64) {
        float tot = partial[0][tid] + partial[1][tid] + partial[2][tid] + partial[3][tid];
        tot = fmaxf(tot, 1.f);
        iscale_g[((size_t)((b * 32 + n) * 8 + h)) * 256 + rtile * 64 + tid] = tot;
        sInvL[tid] = 1.f / tot;
    }
    __syncthreads();

    f32x4 o[8] = {};
    const u16* Vb = vt + (((size_t)((b * 8 + h) * 32 + n)) << 15);
    int kmax = 2 * (rtile + 1);
    for (int kt = 0; kt < kmax; ++kt) {
        s16x8 a = *(const s16x8*)(&Ss[w * 16 + cL][kt * 32 + quad * 8]);
        #pragma unroll
        for (int nt = 0; nt < 8; ++nt) {
            s16x8 bv = *(const s16x8*)(Vb + (nt * 16 + cL) * 256 + kt * 32 + quad * 8);
            o[nt] = MFMA16(a, bv, o[nt]);
        }
    }
    size_t obase = ((size_t)b * 8192 + n * 256 + rtile * 64) * 1024 + h * 128;
    #pragma unroll
    for (int nt = 0; nt < 8; ++nt)
        #pragma unroll
        for (int i = 0; i < 4; ++i) {
            int row = w * 16 + quad * 4 + i;
            ATT[obase + (size_t)row * 1024 + nt * 16 + cL] = f2b(o[nt][i] * sInvL[row]);
        }
}

// ---------------------------------------------------------------------------
// Chunk kv summary, MFMA: kvT[e][kd] = sum_c (vid[c]*V[c][e]) * K[c][kd].
// A = vid-scaled Vt rows (contiguous c); B = K^T via LDS-transposed K tile.
// ---------------------------------------------------------------------------
__global__ __launch_bounds__(256) void chunkkv_mfma(const u16* __restrict__ kr,
                                                    const u16* __restrict__ vt,
                                                    const float* __restrict__ vid,
                                                    float* __restrict__ kvT) {
    __shared__ u16 KtL[64][264];
    int bid = blockIdx.x;
    int h = bid & 7; bid >>= 3;
    int n = bid & 31; int b = bid >> 5;
    int tid = threadIdx.x, lane = tid & 63, w = tid >> 6;
    int cL = lane & 15, quad = lane >> 4;
    const u16* Kb = kr + ((size_t)((b * 8 + h) * 8192 + n * 256)) * 64;
    {
        int c = tid;
        const u16* rp = Kb + c * 64;
        #pragma unroll
        for (int u = 0; u < 8; ++u) {
            s16x8 vv = *(const s16x8*)(rp + u * 8);
            #pragma unroll
            for (int j = 0; j < 8; ++j) KtL[u * 8 + j][c] = (u16)vv[j];
        }
    }
    __syncthreads();
    const u16* Vb = vt + (((size_t)((b * 8 + h) * 32 + n)) << 15);
    f32x4 acc[2][4] = {};
    for (int kt = 0; kt < 8; ++kt) {
        float vidv[8];
        #pragma unroll
        for (int j = 0; j < 8; ++j) vidv[j] = vid[h * 256 + kt * 32 + quad * 8 + j];
        s16x8 af[2];
        #pragma unroll
        for (int mt = 0; mt < 2; ++mt) {
            int e = w * 32 + mt * 16 + cL;
            s16x8 raw = *(const s16x8*)(Vb + e * 256 + kt * 32 + quad * 8);
            #pragma unroll
            for (int j = 0; j < 8; ++j)
                af[mt][j] = (short)f2b(b2f((u16)raw[j]) * vidv[j]);
        }
        #pragma unroll
        for (int nt = 0; nt < 4; ++nt) {
            s16x8 bv = *(const s16x8*)(&KtL[nt * 16 + cL][kt * 32 + quad * 8]);
            #pragma unroll
            for (int mt = 0; mt < 2; ++mt) acc[mt][nt] = MFMA16(af[mt], bv, acc[mt][nt]);
        }
    }
    float* out = kvT + ((size_t)((b * 32 + n) * 8 + h)) * 8192;
    #pragma unroll
    for (int mt = 0; mt < 2; ++mt)
        #pragma unroll
        for (int nt = 0; nt < 4; ++nt)
            #pragma unroll
            for (int i = 0; i < 4; ++i)
                out[(w * 32 + mt * 16 + quad * 4 + i) * 64 + nt * 16 + cL] = acc[mt][nt][i];
}

// ---------------------------------------------------------------------------
// Sequential scan over chunks on kvT layout [e][kd].  Emits kv_rec (pre-
// update state/scale) as bf16 into kvrecb (same layout) + cscale.
// Thread: lane = kd, wave g owns e in {g+4j}.
// ---------------------------------------------------------------------------
__global__ __launch_bounds__(256) void scan_mfma(const float* __restrict__ kvT,
                                                 u16* __restrict__ kvrecb,
                                                 const float* __restrict__ cdv,
                                                 float* __restrict__ cscale) {
    int bh = blockIdx.x;
    int h = bh & 7, b = bh >> 3;
    int tid = threadIdx.x, lane = tid & 63, g = tid >> 6;
    float st[32];
    #pragma unroll
    for (int j = 0; j < 32; ++j) st[j] = 0.f;
    float scale = 1.f;
    float cd = cdv[h];
    __shared__ float esum[128];
    __shared__ float sSc;
    for (int n = 0; n < 32; ++n) {
        size_t base = ((size_t)((b * 32 + n) * 8 + h)) * 8192;
        float inv = 1.f / scale;
        #pragma unroll
        for (int j = 0; j < 32; ++j) {
            int e = g + 4 * j;
            size_t idx = base + e * 64 + lane;
            float kvv = kvT[idx];
            kvrecb[idx] = f2b(st[j] * inv);
            st[j] = st[j] * cd + kvv;
        }
        if (tid == 0) cscale[(b * 32 + n) * 8 + h] = scale;
        #pragma unroll
        for (int j = 0; j < 32; ++j) {
            float s = fabsf(st[j]);
            s += __shfl_xor(s, 1, 64);
            s += __shfl_xor(s, 2, 64);
            s += __shfl_xor(s, 4, 64);
            s += __shfl_xor(s, 8, 64);
            s += __shfl_xor(s, 16, 64);
            s += __shfl_xor(s, 32, 64);
            if (lane == 0) esum[g + 4 * j] = s;
        }
        __syncthreads();
        if (tid < 64) {
            float m1 = fmaxf(esum[tid], esum[tid + 64]);
            m1 = fmaxf(m1, __shfl_xor(m1, 1, 64));
            m1 = fmaxf(m1, __shfl_xor(m1, 2, 64));
            m1 = fmaxf(m1, __shfl_xor(m1, 4, 64));
            m1 = fmaxf(m1, __shfl_xor(m1, 8, 64));
            m1 = fmaxf(m1, __shfl_xor(m1, 16, 64));
            m1 = fmaxf(m1, __shfl_xor(m1, 32, 64));
            if (tid == 0) sSc = fmaxf(m1, 1.f);
        }
        __syncthreads();
        scale = sSc;
    }
}

// ---------------------------------------------------------------------------
// Cross output + combine, MFMA.  Block = (b,n,h), wave owns 64 chunk rows.
// CO = Q.kv_rec (B-frags direct from kvrecb [e][kd] bf16); RMW on ATT.
// ---------------------------------------------------------------------------
__global__ __launch_bounds__(256) void cross_mfma(const u16* __restrict__ qr,
                                                  const u16* __restrict__ kvrecb,
                                                  const float* __restrict__ iscale_g,
                                                  const float* __restrict__ cscale_g,
                                                  const float* __restrict__ qid,
                                                  u16* __restrict__ ATT) {
    int bid = blockIdx.x;
    int h = bid & 7; bid >>= 3;
    int n = bid & 31; int b = bid >> 5;
    int tid = threadIdx.x, lane = tid & 63, w = tid >> 6;
    int cL = lane & 15, quad = lane >> 4;
    const u16* Qb = qr + ((size_t)((b * 8 + h) * 8192 + n * 256 + w * 64)) * 64;
    const u16* KVb = kvrecb + ((size_t)((b * 32 + n) * 8 + h)) * 8192;
    s16x8 af[4][2];
    #pragma unroll
    for (int mt = 0; mt < 4; ++mt)
        #pragma unroll
        for (int kt = 0; kt < 2; ++kt)
            af[mt][kt] = *(const s16x8*)(Qb + (mt * 16 + cL) * 64 + kt * 32 + quad * 8);
    float csc = cscale_g[(b * 32 + n) * 8 + h];
    size_t ibase = ((size_t)((b * 32 + n) * 8 + h)) * 256 + w * 64;
    size_t obase = ((size_t)(b * 8192 + n * 256 + w * 64)) * 1024 + h * 128;
    #pragma unroll
    for (int hn = 0; hn < 2; ++hn) {
        f32x4 acc[4][4] = {};
        #pragma unroll
        for (int kt = 0; kt < 2; ++kt)
            #pragma unroll
            for (int nt = 0; nt < 4; ++nt) {
                int e = (hn * 4 + nt) * 16 + cL;
                s16x8 bv = *(const s16x8*)(KVb + e * 64 + kt * 32 + quad * 8);
                #pragma unroll
                for (int mt = 0; mt < 4; ++mt)
                    acc[mt][nt] = MFMA16(af[mt][kt], bv, acc[mt][nt]);
            }
        #pragma unroll
        for (int mt = 0; mt < 4; ++mt)
            #pragma unroll
            for (int i = 0; i < 4; ++i) {
                int r = mt * 16 + quad * 4 + i;
                float isc = iscale_g[ibase + r];
                float alls = fmaxf(isc, csc);
                float qdv = qid[h * 256 + w * 64 + r];
                float fI = isc / alls;
                float fC = (csc / alls) * qdv;
                #pragma unroll
                for (int nt = 0; nt < 4; ++nt) {
                    int e = (hn * 4 + nt) * 16 + cL;
                    size_t oi = obase + (size_t)r * 1024 + e;
                    float prev = b2f(ATT[oi]);
                    ATT[oi] = f2b(prev * fI + acc[mt][nt][i] * fC);
                }
            }
    }
}

// ---------------------------------------------------------------------------
// PER-HEAD RMS norm (HD=128) + SiLU gate, in place over g.
// ---------------------------------------------------------------------------
__global__ __launch_bounds__(256) void rms_silu(const u16* __restrict__ ATT,
                                                u16* __restrict__ g) {
    int row = blockIdx.x;
    int tid = threadIdx.x;
    size_t base = (size_t)row * 1024 + tid * 4;
    float x[4];
    float ss = 0.f;
    #pragma unroll
    for (int j = 0; j < 4; ++j) {
        x[j] = b2f(ATT[base + j]);
        ss += x[j] * x[j];
    }
    #pragma unroll
    for (int o = 16; o > 0; o >>= 1) ss += __shfl_xor(ss, o, 32);
    float rms = rsqrtf(ss / 128.f + 1e-6f);
    #pragma unroll
    for (int j = 0; j < 4; ++j) {
        float gg = b2f(g[base + j]);
        float sg = gg / (1.f + __expf(-gg));
        g[base + j] = f2b(sg * x[j] * rms);
    }
}

// ---------------------------------------------------------------------------
extern "C" void kernel_launch(void* const* d_in, const int* in_sizes, int n_in,
                              void* d_out, int out_size, void* d_ws, size_t ws_size,
                              hipStream_t stream) {
    const float* x    = (const float*)d_in[0];
    const float* sn   = (const float*)d_in[1];
    const float* cs   = (const float*)d_in[2];
    const float* mask = (const float*)d_in[3];
    const float* cdv  = (const float*)d_in[4];
    const float* qid  = (const float*)d_in[5];
    const float* vid  = (const float*)d_in[6];
    const float* Wq   = (const float*)d_in[7];
    const float* Wk   = (const float*)d_in[8];
    const float* Wv   = (const float*)d_in[9];
    const float* Wg   = (const float*)d_in[10];
    const float* Wo   = (const float*)d_in[11];
    float* out = (float*)d_out;

    // workspace (~223 MB)
    char* w = (char*)d_ws;
    u16* qr     = (u16*)w;   w += (size_t)16777216 * 2;  // 33.5 MB  (B*H*T*KD)
    u16* kr     = (u16*)w;   w += (size_t)16777216 * 2;  // 33.5 MB  (adjacent: qr+kr = gbuf)
    u16* vt     = (u16*)w;   w += (size_t)33554432 * 2;  // 67 MB    (B,H,NC,HD,Cc)
    u16* xbf    = (u16*)w;   w += (size_t)16777216 * 2;  // 33.5 MB
    u16* wqT    = (u16*)w;   w += (size_t)262144 * 2;
    u16* wkT    = (u16*)w;   w += (size_t)262144 * 2;
    u16* wvT    = (u16*)w;   w += (size_t)524288 * 2;
    u16* wgT    = (u16*)w;   w += (size_t)524288 * 2;
    u16* woT    = (u16*)w;   w += (size_t)524288 * 2;
    float* kvT  = (float*)w; w += (size_t)8388608 * 4;   // 33.5 MB
    u16* kvrecb = (u16*)w;   w += (size_t)8388608 * 2;   // 16.8 MB
    float* iscale = (float*)w; w += (size_t)262144 * 4;  // 1 MB
    float* cscale = (float*)w; w += (size_t)1024 * 4;

    u16* gbuf = qr;            // 67 MB over dead qr+kr after cross_combine
    u16* ATT  = (u16*)d_out;   // 67 MB bf16 scratch inside the 134 MB output

    dim3 blk(256);
    // casts
    cast_x_k<<<dim3(16384), blk, 0, stream>>>(x, xbf);
    castT_k<<<dim3(16, 16), blk, 0, stream>>>(Wq, wqT, 512, 512, 1.0f);
    castT_k<<<dim3(16, 16), blk, 0, stream>>>(Wk, wkT, 512, 512, 0.125f);  // KD^-0.5 folded
    castT_k<<<dim3(32, 16), blk, 0, stream>>>(Wv, wvT, 512, 1024, 1.0f);
    castT_k<<<dim3(32, 16), blk, 0, stream>>>(Wg, wgT, 512, 1024, 1.0f);
    castT_k<<<dim3(16, 32), blk, 0, stream>>>(Wo, woT, 1024, 512, 1.0f);
    // projections (rotary/permute/transpose fused in epilogues)
    gemm_mfma<0><<<dim3(4, 256), blk, 0, stream>>>(xbf, wqT, qr, 512, 512, sn, cs);
    gemm_mfma<0><<<dim3(4, 256), blk, 0, stream>>>(xbf, wkT, kr, 512, 512, sn, cs);
    gemm_mfma<1><<<dim3(8, 256), blk, 0, stream>>>(xbf, wvT, vt, 512, 1024, nullptr, nullptr);
    // retention
    attn_mfma<<<dim3(4096), blk, 0, stream>>>(qr, kr, vt, mask, ATT, iscale);
    chunkkv_mfma<<<dim3(1024), blk, 0, stream>>>(kr, vt, vid, kvT);
    scan_mfma<<<dim3(32), blk, 0, stream>>>(kvT, kvrecb, cdv, cscale);
    cross_mfma<<<dim3(1024), blk, 0, stream>>>(qr, kvrecb, iscale, cscale, qid, ATT);
    // epilogue
    gemm_mfma<2><<<dim3(8, 256), blk, 0, stream>>>(xbf, wgT, gbuf, 512, 1024, nullptr, nullptr);
    rms_silu<<<dim3(32768), blk, 0, stream>>>(ATT, gbuf);
    gemm_mfma<3><<<dim3(4, 256), blk, 0, stream>>>(gbuf, woT, out, 1024, 512, nullptr, nullptr);
}

// Round 6
// 1004.633 us; speedup vs baseline: 6.8664x; 1.1699x over previous
//
#include <hip/hip_runtime.h>
#include <cmath>

// Problem constants
#define Bz 4
#define Tt 8192
#define Ee 512
#define Hh 8
#define Cc 256
#define KD 64          // E/H
#define HD 128         // E*VF/H
#define NC 32          // T/C
#define EV 1024        // E*VF
#define Mrows (Bz*Tt)  // 32768

typedef unsigned short u16;
typedef __attribute__((ext_vector_type(4))) float f32x4;
typedef __attribute__((ext_vector_type(8))) short s16x8;

__device__ __forceinline__ u16 f2b(float f) {
    union { float f; unsigned u; } v; v.f = f;
    unsigned r = v.u + 0x7FFFu + ((v.u >> 16) & 1u);
    return (u16)(r >> 16);
}
__device__ __forceinline__ float b2f(u16 u) {
    union { unsigned u; float f; } v; v.u = ((unsigned)u) << 16;
    return v.f;
}
#define MFMA16(a, b, c) __builtin_amdgcn_mfma_f32_16x16x32_bf16((a), (b), (c), 0, 0, 0)

// ---------------------------------------------------------------------------
// cast x (fp32) -> bf16, 4 elems/thread
// ---------------------------------------------------------------------------
__global__ __launch_bounds__(256) void cast_x_k(const float* __restrict__ x,
                                                u16* __restrict__ xb) {
    size_t i = ((size_t)blockIdx.x * 256 + threadIdx.x) * 4;
    float4 v = *(const float4*)(x + i);
    ushort4 o;
    o.x = f2b(v.x); o.y = f2b(v.y); o.z = f2b(v.z); o.w = f2b(v.w);
    *(ushort4*)(xb + i) = o;
}

// ---------------------------------------------------------------------------
// cast + transpose weights: W[K][N] fp32 -> Wt[N][K] bf16 (with scale)
// ---------------------------------------------------------------------------
__global__ __launch_bounds__(256) void castT_k(const float* __restrict__ W,
                                               u16* __restrict__ Wt,
                                               int K, int N, float scale) {
    __shared__ float tile[32][33];
    int k0 = blockIdx.y * 32, n0 = blockIdx.x * 32;
    int r = threadIdx.x >> 3, c4 = (threadIdx.x & 7) * 4;
    float4 v = *(const float4*)(W + (size_t)(k0 + r) * N + n0 + c4);
    tile[r][c4] = v.x; tile[r][c4 + 1] = v.y; tile[r][c4 + 2] = v.z; tile[r][c4 + 3] = v.w;
    __syncthreads();
    ushort4 o;
    o.x = f2b(tile[c4 + 0][r] * scale);
    o.y = f2b(tile[c4 + 1][r] * scale);
    o.z = f2b(tile[c4 + 2][r] * scale);
    o.w = f2b(tile[c4 + 3][r] * scale);
    *(ushort4*)(Wt + (size_t)(n0 + r) * K + k0 + c4) = o;
}

// ---------------------------------------------------------------------------
// MFMA GEMM: C[M,N] = A[M,K](bf16) @ Wt[N,K]^T(bf16).  128x128 tile, 4 waves,
// direct global->VGPR fragments (L1/L2 provide reuse).  Epilogues:
//   EPI=0: rotary + permute to (B,H,T,KD) bf16 (q/k; k-scale folded into Wt)
//   EPI=1: writes Vt[b,h,n][e][c] packed
//   EPI=2: plain bf16 row-major
//   EPI=3: plain fp32 row-major
// ---------------------------------------------------------------------------
template <int EPI>
__global__ __launch_bounds__(256) void gemm_mfma(const u16* __restrict__ A,
                                                 const u16* __restrict__ Bt,
                                                 void* __restrict__ Cout,
                                                 int K, int N,
                                                 const float* __restrict__ sn,
                                                 const float* __restrict__ cs) {
    int tid = threadIdx.x;
    int lane = tid & 63, wid = tid >> 6;
    int cL = lane & 15, quad = lane >> 4;
    int m0 = blockIdx.y * 128 + (wid & 1) * 64;
    int n0 = blockIdx.x * 128 + (wid >> 1) * 64;
    f32x4 acc[4][4] = {};
    for (int k0 = 0; k0 < K; k0 += 32) {
        s16x8 af[4], bfr[4];
        #pragma unroll
        for (int mt = 0; mt < 4; ++mt)
            af[mt] = *(const s16x8*)(A + (size_t)(m0 + mt * 16 + cL) * K + k0 + quad * 8);
        #pragma unroll
        for (int nt = 0; nt < 4; ++nt)
            bfr[nt] = *(const s16x8*)(Bt + (size_t)(n0 + nt * 16 + cL) * K + k0 + quad * 8);
        #pragma unroll
        for (int mt = 0; mt < 4; ++mt)
            #pragma unroll
            for (int nt = 0; nt < 4; ++nt)
                acc[mt][nt] = MFMA16(af[mt], bfr[nt], acc[mt][nt]);
    }
    if (EPI == 0) {
        u16* dst = (u16*)Cout;
        #pragma unroll
        for (int mt = 0; mt < 4; ++mt)
            #pragma unroll
            for (int nt = 0; nt < 4; ++nt)
                #pragma unroll
                for (int i = 0; i < 4; ++i) {
                    int m = m0 + mt * 16 + quad * 4 + i;
                    int n = n0 + nt * 16 + cL;
                    float v = acc[mt][nt][i];
                    float p = __shfl_xor(v, 1, 64);
                    int t = m & 8191, b = m >> 13, h = n >> 6, kd = n & 63;
                    float c1 = cs[t * 64 + kd], s1 = sn[t * 64 + kd];
                    float o = (n & 1) ? (v * c1 + p * s1) : (v * c1 - p * s1);
                    dst[(((size_t)(b * 8 + h)) * 8192 + t) * 64 + kd] = f2b(o);
                }
    } else if (EPI == 1) {
        u16* vt = (u16*)Cout;
        #pragma unroll
        for (int mt = 0; mt < 4; ++mt)
            #pragma unroll
            for (int nt = 0; nt < 4; ++nt) {
                int m = m0 + mt * 16 + quad * 4;  // i=0 row; i=0..3 consecutive t
                int n = n0 + nt * 16 + cL;
                int b = m >> 13, t = m & 8191;
                int nn = t >> 8, ccc = t & 255;
                int h = n >> 7, e = n & 127;
                ushort4 pk;
                pk.x = f2b(acc[mt][nt][0]);
                pk.y = f2b(acc[mt][nt][1]);
                pk.z = f2b(acc[mt][nt][2]);
                pk.w = f2b(acc[mt][nt][3]);
                *(ushort4*)(vt + (((size_t)((b * 8 + h) * 32 + nn)) << 15) + e * 256 + ccc) = pk;
            }
    } else if (EPI == 2) {
        u16* dst = (u16*)Cout;
        #pragma unroll
        for (int mt = 0; mt < 4; ++mt)
            #pragma unroll
            for (int nt = 0; nt < 4; ++nt)
                #pragma unroll
                for (int i = 0; i < 4; ++i)
                    dst[(size_t)(m0 + mt * 16 + quad * 4 + i) * N + n0 + nt * 16 + cL] =
                        f2b(acc[mt][nt][i]);
    } else {
        float* dst = (float*)Cout;
        #pragma unroll
        for (int mt = 0; mt < 4; ++mt)
            #pragma unroll
            for (int nt = 0; nt < 4; ++nt)
                #pragma unroll
                for (int i = 0; i < 4; ++i)
                    dst[(size_t)(m0 + mt * 16 + quad * 4 + i) * N + n0 + nt * 16 + cL] =
                        acc[mt][nt][i];
    }
}

// ---------------------------------------------------------------------------
// Inner retention, MFMA.  Block = (b, n, h, rtile of 64 rows), 4 waves.
// ---------------------------------------------------------------------------
__global__ __launch_bounds__(256) void attn_mfma(const u16* __restrict__ qr,
                                                 const u16* __restrict__ kr,
                                                 const u16* __restrict__ vt,
                                                 const float* __restrict__ mask,
                                                 u16* __restrict__ ATT,
                                                 float* __restrict__ iscale_g) {
    __shared__ u16 Ss[64][264];
    __shared__ float partial[4][64];
    __shared__ float sInvL[64];
    int bid = blockIdx.x;
    int rtile = bid & 3; bid >>= 2;
    int h = bid & 7; bid >>= 3;
    int n = bid & 31; int b = bid >> 5;
    int tid = threadIdx.x, lane = tid & 63, w = tid >> 6;
    int cL = lane & 15, quad = lane >> 4;

    size_t qkbase = ((size_t)((b * 8 + h) * 8192 + n * 256)) * 64;
    f32x4 acc[4][4] = {};
    if (w <= rtile) {
        const u16* Qb = qr + qkbase + (size_t)rtile * 64 * 64;
        const u16* Kb = kr + qkbase + (size_t)w * 64 * 64;
        #pragma unroll
        for (int kt = 0; kt < 2; ++kt) {
            s16x8 af[4], bfr[4];
            #pragma unroll
            for (int mt = 0; mt < 4; ++mt)
                af[mt] = *(const s16x8*)(Qb + (mt * 16 + cL) * 64 + kt * 32 + quad * 8);
            #pragma unroll
            for (int nt = 0; nt < 4; ++nt)
                bfr[nt] = *(const s16x8*)(Kb + (nt * 16 + cL) * 64 + kt * 32 + quad * 8);
            #pragma unroll
            for (int mt = 0; mt < 4; ++mt)
                #pragma unroll
                for (int nt = 0; nt < 4; ++nt)
                    acc[mt][nt] = MFMA16(af[mt], bfr[nt], acc[mt][nt]);
        }
    }
    float rs[4][4] = {};
    if (w <= rtile) {
        const float* mb = mask + ((size_t)h << 16);
        #pragma unroll
        for (int mt = 0; mt < 4; ++mt)
            #pragma unroll
            for (int nt = 0; nt < 4; ++nt)
                #pragma unroll
                for (int i = 0; i < 4; ++i) {
                    int r = rtile * 64 + mt * 16 + quad * 4 + i;
                    int d = w * 64 + nt * 16 + cL;
                    float s = acc[mt][nt][i] * mb[r * 256 + d];
                    Ss[mt * 16 + quad * 4 + i][w * 64 + nt * 16 + cL] = f2b(s);
                    rs[mt][i] += fabsf(s);
                }
    }
    #pragma unroll
    for (int mt = 0; mt < 4; ++mt)
        #pragma unroll
        for (int i = 0; i < 4; ++i) {
            float v = rs[mt][i];
            v += __shfl_xor(v, 1, 16);
            v += __shfl_xor(v, 2, 16);
            v += __shfl_xor(v, 4, 16);
            v += __shfl_xor(v, 8, 16);
            if (cL == 0) partial[w][mt * 16 + quad * 4 + i] = v;
        }
    __syncthreads();
    if (tid < 64) {
        float tot = partial[0][tid] + partial[1][tid] + partial[2][tid] + partial[3][tid];
        tot = fmaxf(tot, 1.f);
        iscale_g[((size_t)((b * 32 + n) * 8 + h)) * 256 + rtile * 64 + tid] = tot;
        sInvL[tid] = 1.f / tot;
    }
    __syncthreads();

    f32x4 o[8] = {};
    const u16* Vb = vt + (((size_t)((b * 8 + h) * 32 + n)) << 15);
    int kmax = 2 * (rtile + 1);
    for (int kt = 0; kt < kmax; ++kt) {
        s16x8 a = *(const s16x8*)(&Ss[w * 16 + cL][kt * 32 + quad * 8]);
        #pragma unroll
        for (int nt = 0; nt < 8; ++nt) {
            s16x8 bv = *(const s16x8*)(Vb + (nt * 16 + cL) * 256 + kt * 32 + quad * 8);
            o[nt] = MFMA16(a, bv, o[nt]);
        }
    }
    size_t obase = ((size_t)b * 8192 + n * 256 + rtile * 64) * 1024 + h * 128;
    #pragma unroll
    for (int nt = 0; nt < 8; ++nt)
        #pragma unroll
        for (int i = 0; i < 4; ++i) {
            int row = w * 16 + quad * 4 + i;
            ATT[obase + (size_t)row * 1024 + nt * 16 + cL] = f2b(o[nt][i] * sInvL[row]);
        }
}

// ---------------------------------------------------------------------------
// Chunk kv summary, MFMA: kvT[e][kd] = sum_c (vid[c]*V[c][e]) * K[c][kd].
// ---------------------------------------------------------------------------
__global__ __launch_bounds__(256) void chunkkv_mfma(const u16* __restrict__ kr,
                                                    const u16* __restrict__ vt,
                                                    const float* __restrict__ vid,
                                                    float* __restrict__ kvT) {
    __shared__ u16 KtL[64][264];
    int bid = blockIdx.x;
    int h = bid & 7; bid >>= 3;
    int n = bid & 31; int b = bid >> 5;
    int tid = threadIdx.x, lane = tid & 63, w = tid >> 6;
    int cL = lane & 15, quad = lane >> 4;
    const u16* Kb = kr + ((size_t)((b * 8 + h) * 8192 + n * 256)) * 64;
    {
        int c = tid;
        const u16* rp = Kb + c * 64;
        #pragma unroll
        for (int u = 0; u < 8; ++u) {
            s16x8 vv = *(const s16x8*)(rp + u * 8);
            #pragma unroll
            for (int j = 0; j < 8; ++j) KtL[u * 8 + j][c] = (u16)vv[j];
        }
    }
    __syncthreads();
    const u16* Vb = vt + (((size_t)((b * 8 + h) * 32 + n)) << 15);
    f32x4 acc[2][4] = {};
    for (int kt = 0; kt < 8; ++kt) {
        float vidv[8];
        #pragma unroll
        for (int j = 0; j < 8; ++j) vidv[j] = vid[h * 256 + kt * 32 + quad * 8 + j];
        s16x8 af[2];
        #pragma unroll
        for (int mt = 0; mt < 2; ++mt) {
            int e = w * 32 + mt * 16 + cL;
            s16x8 raw = *(const s16x8*)(Vb + e * 256 + kt * 32 + quad * 8);
            #pragma unroll
            for (int j = 0; j < 8; ++j)
                af[mt][j] = (short)f2b(b2f((u16)raw[j]) * vidv[j]);
        }
        #pragma unroll
        for (int nt = 0; nt < 4; ++nt) {
            s16x8 bv = *(const s16x8*)(&KtL[nt * 16 + cL][kt * 32 + quad * 8]);
            #pragma unroll
            for (int mt = 0; mt < 2; ++mt) acc[mt][nt] = MFMA16(af[mt], bv, acc[mt][nt]);
        }
    }
    float* out = kvT + ((size_t)((b * 32 + n) * 8 + h)) * 8192;
    #pragma unroll
    for (int mt = 0; mt < 2; ++mt)
        #pragma unroll
        for (int nt = 0; nt < 4; ++nt)
            #pragma unroll
            for (int i = 0; i < 4; ++i)
                out[(w * 32 + mt * 16 + quad * 4 + i) * 64 + nt * 16 + cL] = acc[mt][nt][i];
}

// ---------------------------------------------------------------------------
// PARALLEL scan: one block per (b,h,n).  S_{n-1} = sum_{j<n} cd^{n-1-j} kv_j
// accumulated in registers (iterate j ascending: S = S*cd + kv_j).  Block-
// reduce |S| (sum over kd, max over e, clip 1) -> scale_{n-1}; emit
// kvrecb_n = S_{n-1}/scale_{n-1} (bf16) and cscale_n = scale_{n-1}.
// Independent blocks: no serial chain; kvT (33 MB) is L3-resident.
// ---------------------------------------------------------------------------
__global__ __launch_bounds__(256) void scan_par(const float* __restrict__ kvT,
                                                u16* __restrict__ kvrecb,
                                                const float* __restrict__ cdv,
                                                float* __restrict__ cscale) {
    int bid = blockIdx.x;
    int n = bid & 31; bid >>= 5;
    int h = bid & 7; int b = bid >> 3;
    int tid = threadIdx.x, lane = tid & 63, g = tid >> 6;
    float cd = cdv[h];
    float st[32];
    #pragma unroll
    for (int i = 0; i < 32; ++i) st[i] = 0.f;
    for (int j = 0; j < n; ++j) {
        size_t base = ((size_t)((b * 32 + j) * 8 + h)) * 8192;
        #pragma unroll
        for (int i = 0; i < 32; ++i) {
            int e = g + 4 * i;
            st[i] = st[i] * cd + kvT[base + e * 64 + lane];
        }
    }
    // scale = max(1, max_e sum_kd |S|)
    __shared__ float esum[128];
    __shared__ float sSc;
    #pragma unroll
    for (int i = 0; i < 32; ++i) {
        float s = fabsf(st[i]);
        s += __shfl_xor(s, 1, 64);
        s += __shfl_xor(s, 2, 64);
        s += __shfl_xor(s, 4, 64);
        s += __shfl_xor(s, 8, 64);
        s += __shfl_xor(s, 16, 64);
        s += __shfl_xor(s, 32, 64);
        if (lane == 0) esum[g + 4 * i] = s;
    }
    __syncthreads();
    if (tid < 64) {
        float m1 = fmaxf(esum[tid], esum[tid + 64]);
        m1 = fmaxf(m1, __shfl_xor(m1, 1, 64));
        m1 = fmaxf(m1, __shfl_xor(m1, 2, 64));
        m1 = fmaxf(m1, __shfl_xor(m1, 4, 64));
        m1 = fmaxf(m1, __shfl_xor(m1, 8, 64));
        m1 = fmaxf(m1, __shfl_xor(m1, 16, 64));
        m1 = fmaxf(m1, __shfl_xor(m1, 32, 64));
        if (tid == 0) sSc = fmaxf(m1, 1.f);
    }
    __syncthreads();
    float scale = sSc;
    float inv = 1.f / scale;
    size_t baseN = ((size_t)((b * 32 + n) * 8 + h)) * 8192;
    #pragma unroll
    for (int i = 0; i < 32; ++i) {
        int e = g + 4 * i;
        kvrecb[baseN + e * 64 + lane] = f2b(st[i] * inv);
    }
    if (tid == 0) cscale[(b * 32 + n) * 8 + h] = scale;
}

// ---------------------------------------------------------------------------
// Cross output + combine, MFMA.  Block = (b,n,h), wave owns 64 chunk rows.
// ---------------------------------------------------------------------------
__global__ __launch_bounds__(256) void cross_mfma(const u16* __restrict__ qr,
                                                  const u16* __restrict__ kvrecb,
                                                  const float* __restrict__ iscale_g,
                                                  const float* __restrict__ cscale_g,
                                                  const float* __restrict__ qid,
                                                  u16* __restrict__ ATT) {
    int bid = blockIdx.x;
    int h = bid & 7; bid >>= 3;
    int n = bid & 31; int b = bid >> 5;
    int tid = threadIdx.x, lane = tid & 63, w = tid >> 6;
    int cL = lane & 15, quad = lane >> 4;
    const u16* Qb = qr + ((size_t)((b * 8 + h) * 8192 + n * 256 + w * 64)) * 64;
    const u16* KVb = kvrecb + ((size_t)((b * 32 + n) * 8 + h)) * 8192;
    s16x8 af[4][2];
    #pragma unroll
    for (int mt = 0; mt < 4; ++mt)
        #pragma unroll
        for (int kt = 0; kt < 2; ++kt)
            af[mt][kt] = *(const s16x8*)(Qb + (mt * 16 + cL) * 64 + kt * 32 + quad * 8);
    float csc = cscale_g[(b * 32 + n) * 8 + h];
    size_t ibase = ((size_t)((b * 32 + n) * 8 + h)) * 256 + w * 64;
    size_t obase = ((size_t)(b * 8192 + n * 256 + w * 64)) * 1024 + h * 128;
    #pragma unroll
    for (int hn = 0; hn < 2; ++hn) {
        f32x4 acc[4][4] = {};
        #pragma unroll
        for (int kt = 0; kt < 2; ++kt)
            #pragma unroll
            for (int nt = 0; nt < 4; ++nt) {
                int e = (hn * 4 + nt) * 16 + cL;
                s16x8 bv = *(const s16x8*)(KVb + e * 64 + kt * 32 + quad * 8);
                #pragma unroll
                for (int mt = 0; mt < 4; ++mt)
                    acc[mt][nt] = MFMA16(af[mt][kt], bv, acc[mt][nt]);
            }
        #pragma unroll
        for (int mt = 0; mt < 4; ++mt)
            #pragma unroll
            for (int i = 0; i < 4; ++i) {
                int r = mt * 16 + quad * 4 + i;
                float isc = iscale_g[ibase + r];
                float alls = fmaxf(isc, csc);
                float qdv = qid[h * 256 + w * 64 + r];
                float fI = isc / alls;
                float fC = (csc / alls) * qdv;
                #pragma unroll
                for (int nt = 0; nt < 4; ++nt) {
                    int e = (hn * 4 + nt) * 16 + cL;
                    size_t oi = obase + (size_t)r * 1024 + e;
                    float prev = b2f(ATT[oi]);
                    ATT[oi] = f2b(prev * fI + acc[mt][nt][i] * fC);
                }
            }
    }
}

// ---------------------------------------------------------------------------
// PER-HEAD RMS norm (HD=128) + SiLU gate, in place over g.
// ---------------------------------------------------------------------------
__global__ __launch_bounds__(256) void rms_silu(const u16* __restrict__ ATT,
                                                u16* __restrict__ g) {
    int row = blockIdx.x;
    int tid = threadIdx.x;
    size_t base = (size_t)row * 1024 + tid * 4;
    float x[4];
    float ss = 0.f;
    #pragma unroll
    for (int j = 0; j < 4; ++j) {
        x[j] = b2f(ATT[base + j]);
        ss += x[j] * x[j];
    }
    #pragma unroll
    for (int o = 16; o > 0; o >>= 1) ss += __shfl_xor(ss, o, 32);
    float rms = rsqrtf(ss / 128.f + 1e-6f);
    #pragma unroll
    for (int j = 0; j < 4; ++j) {
        float gg = b2f(g[base + j]);
        float sg = gg / (1.f + __expf(-gg));
        g[base + j] = f2b(sg * x[j] * rms);
    }
}

// ---------------------------------------------------------------------------
extern "C" void kernel_launch(void* const* d_in, const int* in_sizes, int n_in,
                              void* d_out, int out_size, void* d_ws, size_t ws_size,
                              hipStream_t stream) {
    const float* x    = (const float*)d_in[0];
    const float* sn   = (const float*)d_in[1];
    const float* cs   = (const float*)d_in[2];
    const float* mask = (const float*)d_in[3];
    const float* cdv  = (const float*)d_in[4];
    const float* qid  = (const float*)d_in[5];
    const float* vid  = (const float*)d_in[6];
    const float* Wq   = (const float*)d_in[7];
    const float* Wk   = (const float*)d_in[8];
    const float* Wv   = (const float*)d_in[9];
    const float* Wg   = (const float*)d_in[10];
    const float* Wo   = (const float*)d_in[11];
    float* out = (float*)d_out;

    // workspace (~214 MB)
    char* w = (char*)d_ws;
    u16* qr     = (u16*)w;   w += (size_t)16777216 * 2;  // 33.5 MB  (B*H*T*KD)
    u16* kr     = (u16*)w;   w += (size_t)16777216 * 2;  // 33.5 MB  (adjacent: qr+kr = gbuf)
    u16* vt     = (u16*)w;   w += (size_t)33554432 * 2;  // 67 MB    (B,H,NC,HD,Cc)
    u16* xbf    = (u16*)w;   w += (size_t)16777216 * 2;  // 33.5 MB
    u16* wqT    = (u16*)w;   w += (size_t)262144 * 2;
    u16* wkT    = (u16*)w;   w += (size_t)262144 * 2;
    u16* wvT    = (u16*)w;   w += (size_t)524288 * 2;
    u16* wgT    = (u16*)w;   w += (size_t)524288 * 2;
    u16* woT    = (u16*)w;   w += (size_t)524288 * 2;
    float* kvT  = (float*)w; w += (size_t)8388608 * 4;   // 33.5 MB
    u16* kvrecb = (u16*)w;   w += (size_t)8388608 * 2;   // 16.8 MB
    float* iscale = (float*)w; w += (size_t)262144 * 4;  // 1 MB
    float* cscale = (float*)w; w += (size_t)1024 * 4;

    u16* gbuf = qr;            // 67 MB over dead qr+kr after cross_combine
    u16* ATT  = (u16*)d_out;   // 67 MB bf16 scratch inside the output buffer

    dim3 blk(256);
    // casts
    cast_x_k<<<dim3(16384), blk, 0, stream>>>(x, xbf);
    castT_k<<<dim3(16, 16), blk, 0, stream>>>(Wq, wqT, 512, 512, 1.0f);
    castT_k<<<dim3(16, 16), blk, 0, stream>>>(Wk, wkT, 512, 512, 0.125f);  // KD^-0.5 folded
    castT_k<<<dim3(32, 16), blk, 0, stream>>>(Wv, wvT, 512, 1024, 1.0f);
    castT_k<<<dim3(32, 16), blk, 0, stream>>>(Wg, wgT, 512, 1024, 1.0f);
    castT_k<<<dim3(16, 32), blk, 0, stream>>>(Wo, woT, 1024, 512, 1.0f);
    // projections (rotary/permute/transpose fused in epilogues)
    gemm_mfma<0><<<dim3(4, 256), blk, 0, stream>>>(xbf, wqT, qr, 512, 512, sn, cs);
    gemm_mfma<0><<<dim3(4, 256), blk, 0, stream>>>(xbf, wkT, kr, 512, 512, sn, cs);
    gemm_mfma<1><<<dim3(8, 256), blk, 0, stream>>>(xbf, wvT, vt, 512, 1024, nullptr, nullptr);
    // retention
    attn_mfma<<<dim3(4096), blk, 0, stream>>>(qr, kr, vt, mask, ATT, iscale);
    chunkkv_mfma<<<dim3(1024), blk, 0, stream>>>(kr, vt, vid, kvT);
    scan_par<<<dim3(1024), blk, 0, stream>>>(kvT, kvrecb, cdv, cscale);
    cross_mfma<<<dim3(1024), blk, 0, stream>>>(qr, kvrecb, iscale, cscale, qid, ATT);
    // epilogue
    gemm_mfma<2><<<dim3(8, 256), blk, 0, stream>>>(xbf, wgT, gbuf, 512, 1024, nullptr, nullptr);
    rms_silu<<<dim3(32768), blk, 0, stream>>>(ATT, gbuf);
    gemm_mfma<3><<<dim3(4, 256), blk, 0, stream>>>(gbuf, woT, out, 1024, 512, nullptr, nullptr);
}